// Round 6
// baseline (333.299 us; speedup 1.0000x reference)
//
#include <hip/hip_runtime.h>
#include <math.h>

#define DIM 480          // 128*1 + 64*3 + 32*5
#define ROWS 8           // rows per tile
#define BLOCK 64         // one wave per block: no __syncthreads anywhere
#define NV 15            // f4 per lane per tile (ROWS*DIM/4/64)
#define TILE_F4 (ROWS * DIM / 4)   // 960 f4 per tile
#define NBLOCKS 2560     // 10 resident 15KB wave-blocks per CU x 256 CU

typedef float f4 __attribute__((ext_vector_type(4)));

// scaling = silu(max(n,eps))/max(n,eps) == sigmoid(max(n,eps))
__device__ __forceinline__ float sig_of(float n) {
    n = fmaxf(n, 1e-8f);
    return __builtin_amdgcn_rcpf(1.0f + __expf(-n));
}

// Scale all groups of ROWS rows in-place in LDS.
// Bank analysis (32 banks, row stride 480 == 0 mod 32):
//   A: b128 unit-stride RMW -> conflict-free
//   B: stride 3, C: stride 5 (gcd=1 with 32) -> <=2-way aliasing (free, m136)
template <int R>
__device__ __forceinline__ void scale_groups(float* sbuf, int lane) {
    #pragma unroll
    for (int k = 0; k < R / 2; ++k) {            // region A: d=1, 4 groups/f4
        const int a4 = k * 64 + lane;
        f4* p = (f4*)(sbuf + (a4 >> 5) * DIM) + (a4 & 31);
        f4 x = *p;
        x.x *= sig_of(fabsf(x.x));
        x.y *= sig_of(fabsf(x.y));
        x.z *= sig_of(fabsf(x.z));
        x.w *= sig_of(fabsf(x.w));
        *p = x;
    }
    #pragma unroll
    for (int k = 0; k < R; ++k) {                // region B: d=3
        const int b = k * 64 + lane;
        float* p = sbuf + (b >> 6) * DIM + 128 + 3 * (b & 63);
        const float x0 = p[0], x1 = p[1], x2 = p[2];
        const float s = sig_of(sqrtf(x0*x0 + x1*x1 + x2*x2));
        p[0] = x0 * s; p[1] = x1 * s; p[2] = x2 * s;
    }
    #pragma unroll
    for (int k = 0; k < R / 2; ++k) {            // region C: d=5
        const int c = k * 64 + lane;
        float* p = sbuf + (c >> 5) * DIM + 320 + 5 * (c & 31);
        const float x0 = p[0], x1 = p[1], x2 = p[2], x3 = p[3], x4 = p[4];
        const float s = sig_of(sqrtf(x0*x0 + x1*x1 + x2*x2 + x3*x3 + x4*x4));
        p[0] = x0*s; p[1] = x1*s; p[2] = x2*s; p[3] = x3*s; p[4] = x4*s;
    }
}

__device__ void scale_groups_rt(float* sbuf, int lane, int rows) {
    for (int a = lane; a < rows * 128; a += 64) {
        float* p = sbuf + (a >> 7) * DIM + (a & 127);
        const float x = *p;
        *p = x * sig_of(fabsf(x));
    }
    for (int b = lane; b < rows * 64; b += 64) {
        float* p = sbuf + (b >> 6) * DIM + 128 + 3 * (b & 63);
        const float x0 = p[0], x1 = p[1], x2 = p[2];
        const float s = sig_of(sqrtf(x0*x0 + x1*x1 + x2*x2));
        p[0] = x0 * s; p[1] = x1 * s; p[2] = x2 * s;
    }
    for (int c = lane; c < rows * 32; c += 64) {
        float* p = sbuf + (c >> 5) * DIM + 320 + 5 * (c & 31);
        const float x0 = p[0], x1 = p[1], x2 = p[2], x3 = p[3], x4 = p[4];
        const float s = sig_of(sqrtf(x0*x0 + x1*x1 + x2*x2 + x3*x3 + x4*x4));
        p[0] = x0*s; p[1] = x1*s; p[2] = x2*s; p[3] = x3*s; p[4] = x4*s;
    }
}

// Issue the 15 coalesced f4 loads of a tile into a register set.
// Fully unrolled, static indices -> stays in VGPRs (no scratch).
__device__ __forceinline__ void load_tile(const f4* __restrict__ gsrc,
                                          int lane, f4 r[NV]) {
    #pragma unroll
    for (int k = 0; k < NV; ++k) r[k] = gsrc[k * 64 + lane];
}

// regs -> LDS -> in-place scale -> LDS -> nt store. The NEXT tile's global
// loads (issued by the caller before this) stay in flight across all of it:
// no global_load_lds DMA means the compiler emits counted vmcnt per-use
// waits instead of a conservative vmcnt(0) drain.
__device__ __forceinline__ void process_tile(const f4 r[NV], float* sbuf,
                                             f4* __restrict__ gdst, int lane) {
    #pragma unroll
    for (int k = 0; k < NV; ++k)
        ((f4*)sbuf)[k * 64 + lane] = r[k];        // ds_write_b128, conflict-free
    scale_groups<ROWS>(sbuf, lane);               // compiler inserts lgkmcnt
    #pragma unroll
    for (int k = 0; k < NV; ++k)
        __builtin_nontemporal_store(((const f4*)sbuf)[k * 64 + lane],
                                    gdst + k * 64 + lane);
}

__global__ __launch_bounds__(BLOCK) void norm_act_kernel(
    const float* __restrict__ in, float* __restrict__ out, int n_rows)
{
    __shared__ __align__(16) float sbuf[ROWS * DIM];   // 15360 B -> 10 blocks/CU
    const int lane   = threadIdx.x;
    const int stride = gridDim.x;
    const int nfull  = n_rows / ROWS;              // 12500 full tiles
    const f4* gin  = (const f4*)in;
    f4*       gout = (f4*)out;

    f4 ra[NV], rb[NV];

    int t = blockIdx.x;
    if (t < nfull) {
        load_tile(gin + (size_t)t * TILE_F4, lane, ra);      // prologue
        for (;;) {
            const int t2 = t + stride;
            if (t2 >= nfull) {
                process_tile(ra, sbuf, gout + (size_t)t * TILE_F4, lane);
                break;
            }
            load_tile(gin + (size_t)t2 * TILE_F4, lane, rb); // issue early
            process_tile(ra, sbuf, gout + (size_t)t * TILE_F4, lane);
            const int t3 = t2 + stride;
            if (t3 >= nfull) {
                process_tile(rb, sbuf, gout + (size_t)t2 * TILE_F4, lane);
                break;
            }
            load_tile(gin + (size_t)t3 * TILE_F4, lane, ra); // issue early
            process_tile(rb, sbuf, gout + (size_t)t2 * TILE_F4, lane);
            t = t3;
        }
    }

    // partial tail tile (not hit for n_rows=100000): owner block handles it
    const int rem = n_rows - nfull * ROWS;
    if (rem > 0 && (int)blockIdx.x == (nfull % stride)) {
        const float* gsrc = in  + (size_t)nfull * ROWS * DIM;
        float*       gdst = out + (size_t)nfull * ROWS * DIM;
        for (int v = lane; v < rem * (DIM / 4); v += BLOCK)
            ((f4*)sbuf)[v] = ((const f4*)gsrc)[v];
        scale_groups_rt(sbuf, lane, rem);
        for (int v = lane; v < rem * (DIM / 4); v += BLOCK)
            __builtin_nontemporal_store(((const f4*)sbuf)[v], (f4*)gdst + v);
    }
}

extern "C" void kernel_launch(void* const* d_in, const int* in_sizes, int n_in,
                              void* d_out, int out_size, void* d_ws, size_t ws_size,
                              hipStream_t stream) {
    const float* in  = (const float*)d_in[0];
    float*       out = (float*)d_out;
    const int n_rows = in_sizes[0] / DIM;                    // 100000
    const int ntiles = (n_rows + ROWS - 1) / ROWS;           // 12500
    const int grid   = ntiles < NBLOCKS ? ntiles : NBLOCKS;  // persistent waves
    norm_act_kernel<<<grid, BLOCK, 0, stream>>>(in, out, n_rows);
}

// Round 7
// 333.016 us; speedup vs baseline: 1.0009x; 1.0009x over previous
//
#include <hip/hip_runtime.h>
#include <math.h>

#define DIM 480          // 128*1 + 64*3 + 32*5  = 120 float4 per row
#define BLOCK 256        // 4 autonomous waves per block; NO LDS, NO barriers
#define NBLOCKS 2048     // 8 blocks/CU x 256 CU -> 32 waves/CU (full occupancy)

typedef float f4 __attribute__((ext_vector_type(4)));

// scaling = silu(max(n,eps))/max(n,eps) == sigmoid(max(n,eps))
__device__ __forceinline__ float sig_of(float n) {
    n = fmaxf(n, 1e-8f);
    return __builtin_amdgcn_rcpf(1.0f + __expf(-n));
}

// Layout (per row, in f4 units): A = [0,32)  B = [32,80)  C = [80,120)
//   A: 4 singleton (d=1) groups per f4 -> lane-local.
//   B: cluster = 3 f4 = 12 floats = 4 groups of d=3. 3 lanes/cluster.
//   C: cluster = 5 f4 = 20 floats = 4 groups of d=5. 5 lanes/cluster.
// Group sums complete via nearest-neighbor lane partials (__shfl = ds_bpermute,
// no LDS allocation) -> occupancy is VGPR-bound only (32 waves/CU).
__global__ __launch_bounds__(BLOCK) void norm_act_kernel(
    const float* __restrict__ in, float* __restrict__ out, int n_rows)
{
    const int l  = threadIdx.x & 63;
    const int gw = blockIdx.x * (BLOCK / 64) + (threadIdx.x >> 6);
    const int ws = gridDim.x * (BLOCK / 64);

    const f4* gin  = (const f4*)in;
    f4*       gout = (f4*)out;

    const int nA4 = n_rows * 32;          // A f4 count
    const int NB  = n_rows * 16;          // B clusters
    const int NC  = n_rows * 8;           // C clusters
    const int WA  = (nA4 + 63) >> 6;      // wave-iters per region
    const int WB  = (NB + 20) / 21;       // 21 clusters (63 lanes) per wave
    const int WC  = (NC + 11) / 12;       // 12 clusters (60 lanes) per wave
    const int WT  = WA + WB + WC;

    for (int w = gw; w < WT; w += ws) {   // wave-uniform region branch
        if (w < WA) {
            // ---------------- region A ----------------
            const int a = (w << 6) + l;
            if (a < nA4) {
                const size_t j = (size_t)(a >> 5) * 120 + (a & 31);
                f4 x = gin[j];
                x.x *= sig_of(fabsf(x.x));
                x.y *= sig_of(fabsf(x.y));
                x.z *= sig_of(fabsf(x.z));
                x.w *= sig_of(fabsf(x.w));
                __builtin_nontemporal_store(x, gout + j);
            }
        } else if (w < WA + WB) {
            // ---------------- region B (d=3) ----------------
            const int cl = l / 3;                    // cluster-in-wave, lane 63 idle
            const int p  = l - cl * 3;               // f4 phase in cluster
            const int c  = (w - WA) * 21 + cl;
            const bool act = (l < 63) && (c < NB);
            const size_t j = (size_t)(c >> 4) * 120 + 32 + 3 * (c & 15) + p;
            f4 x = {0.f, 0.f, 0.f, 0.f};
            if (act) x = gin[j];
            const float q0 = x.x*x.x, q1 = x.y*x.y, q2 = x.z*x.z, q3 = x.w*x.w;
            // partials: lo -> lane's earlier group, hi -> later group
            // p0: lo=q0+q1+q2 hi=q3 | p1: lo=q0+q1 hi=q2+q3 | p2: lo=q0 hi=q1+q2+q3
            const float lo = q0 + (p < 2 ? q1 : 0.f) + (p == 0 ? q2 : 0.f);
            const float hi = q3 + (p > 0 ? q2 : 0.f) + (p == 2 ? q1 : 0.f);
            const float prev_hi = __shfl(hi, (l - 1) & 63);
            const float next_lo = __shfl(lo, (l + 1) & 63);
            const float gA = lo + (p == 0 ? 0.f : prev_hi);  // full earlier-group sum
            const float gB = hi + (p == 2 ? 0.f : next_lo);  // full later-group sum
            const float sA = sig_of(sqrtf(gA));
            const float sB = sig_of(sqrtf(gB));
            x.x *= sA;                       // comps 0..m-1 use sA, m = 3,2,1 by phase
            x.y *= (p < 2)  ? sA : sB;
            x.z *= (p == 0) ? sA : sB;
            x.w *= sB;
            if (act) __builtin_nontemporal_store(x, gout + j);
        } else {
            // ---------------- region C (d=5) ----------------
            const int cl = l / 5;                    // lanes 60..63 idle
            const int p  = l - cl * 5;
            const int c  = (w - WA - WB) * 12 + cl;
            const bool act = (l < 60) && (c < NC);
            const size_t j = (size_t)(c >> 3) * 120 + 80 + 5 * (c & 7) + p;
            f4 x = {0.f, 0.f, 0.f, 0.f};
            if (act) x = gin[j];
            const float q0 = x.x*x.x, q1 = x.y*x.y, q2 = x.z*x.z, q3 = x.w*x.w;
            // comps belonging to lane's earlier group: t = 4,1,2,3,4 for p=0..4
            const int t = (p == 0 || p == 4) ? 4 : p;
            const float lo = q0 + (t > 1 ? q1 : 0.f) + (t > 2 ? q2 : 0.f)
                                + (t > 3 ? q3 : 0.f);
            const float hi = (q0 + q1 + q2 + q3) - lo;   // all-positive: no cancel
            const float prev_lo = __shfl(lo, (l - 1) & 63);
            const float prev_hi = __shfl(hi, (l - 1) & 63);
            const float next_lo = __shfl(lo, (l + 1) & 63);
            // earlier-group full sum:
            //   p0: lo+next_lo | p1: prev_lo+lo | p2..4: prev_hi+lo
            const float gA = lo + (p == 0 ? next_lo : (p == 1 ? prev_lo : prev_hi));
            // later-group full sum (p1..3): hi + next_lo; p0/p4 have no later group
            const float gB = (p == 0 || p == 4) ? gA : hi + next_lo;
            const float sA = sig_of(sqrtf(gA));
            const float sB = sig_of(sqrtf(gB));
            x.x *= sA;
            x.y *= (t > 1) ? sA : sB;
            x.z *= (t > 2) ? sA : sB;
            x.w *= (t > 3) ? sA : sB;
            if (act) __builtin_nontemporal_store(x, gout + j);
        }
    }
}

extern "C" void kernel_launch(void* const* d_in, const int* in_sizes, int n_in,
                              void* d_out, int out_size, void* d_ws, size_t ws_size,
                              hipStream_t stream) {
    const float* in  = (const float*)d_in[0];
    float*       out = (float*)d_out;
    const int n_rows = in_sizes[0] / DIM;     // 100000
    norm_act_kernel<<<NBLOCKS, BLOCK, 0, stream>>>(in, out, n_rows);
}